// Round 1
// baseline (209.733 us; speedup 1.0000x reference)
//
#include <hip/hip_runtime.h>

#define HH 16
#define DD 128
#define NBQ 128

typedef __attribute__((ext_vector_type(4))) float f32x4;
typedef __attribute__((ext_vector_type(8))) short bf16x8;

__device__ __forceinline__ unsigned short f2bf(float f) {
  unsigned u = __builtin_bit_cast(unsigned, f);
  u += 0x7fff + ((u >> 16) & 1);   // round-to-nearest-even
  return (unsigned short)(u >> 16);
}

__global__ __launch_bounds__(256, 2)
void sparse_attn_kernel(const float* __restrict__ qg, const float* __restrict__ kg,
                        const float* __restrict__ vg, const int* __restrict__ kidx,
                        float* __restrict__ outg, int kmax) {
  // LDS: Ks [64][128] bf16 swizzled (16KB) | Vt [128][64] bf16 swizzled (16KB)
  //      | P  per-wave [16][64] bf16 swizzled (4 x 2KB)
  __shared__ __align__(16) char lds[40960];
  char* Ks = lds;
  char* Vt = lds + 16384;

  const int qb   = blockIdx.x;   // query block 0..127
  const int h    = blockIdx.y;   // head 0..15
  const int tid  = threadIdx.x;
  const int wid  = tid >> 6;     // wave 0..3 -> q rows wid*16..wid*16+15
  const int lane = tid & 63;
  const int l15  = lane & 15;
  const int lg   = lane >> 4;    // 0..3
  char* Pl = lds + 32768 + wid * 2048;

  const float scale = 0.08838834764831845f;  // 1/sqrt(128)

  // ---- load Q fragments (A operand), scale folded in ----
  bf16x8 qa[4];
  {
    const float* qp = qg + ((size_t)(qb * 64 + wid * 16 + l15) * HH + h) * DD;
    #pragma unroll
    for (int kc = 0; kc < 4; ++kc) {
      const int d0 = kc * 32 + lg * 8;
      f32x4 a = *(const f32x4*)(qp + d0);
      f32x4 b = *(const f32x4*)(qp + d0 + 4);
      bf16x8 f;
      f[0] = (short)f2bf(a[0] * scale); f[1] = (short)f2bf(a[1] * scale);
      f[2] = (short)f2bf(a[2] * scale); f[3] = (short)f2bf(a[3] * scale);
      f[4] = (short)f2bf(b[0] * scale); f[5] = (short)f2bf(b[1] * scale);
      f[6] = (short)f2bf(b[2] * scale); f[7] = (short)f2bf(b[3] * scale);
      qa[kc] = f;
    }
  }

  f32x4 oa[8];
  #pragma unroll
  for (int i = 0; i < 8; ++i) oa[i] = (f32x4){0.f, 0.f, 0.f, 0.f};
  float mr[4] = {-1e30f, -1e30f, -1e30f, -1e30f};
  float lr[4] = {0.f, 0.f, 0.f, 0.f};

  const int* krow = kidx + (size_t)qb * kmax;
  for (int t = 0; t < kmax; ++t) {
    const int kb = krow[t];
    if (t > 0 && kb == 0) continue;  // padding entry (uniform across workgroup)

    __syncthreads();  // previous iteration's LDS reads done before overwrite

    // ---- stage K block: row-major bf16 [64][128], XOR-swizzled ----
    {
      const int r  = tid >> 2;
      const int dc = (tid & 3) * 32;
      const float* kp = kg + ((size_t)(kb * 64 + r) * HH + h) * DD + dc;
      #pragma unroll
      for (int c = 0; c < 4; ++c) {
        f32x4 a = *(const f32x4*)(kp + c * 8);
        f32x4 b = *(const f32x4*)(kp + c * 8 + 4);
        bf16x8 f;
        f[0] = (short)f2bf(a[0]); f[1] = (short)f2bf(a[1]);
        f[2] = (short)f2bf(a[2]); f[3] = (short)f2bf(a[3]);
        f[4] = (short)f2bf(b[0]); f[5] = (short)f2bf(b[1]);
        f[6] = (short)f2bf(b[2]); f[7] = (short)f2bf(b[3]);
        const int off = (r * 256 + (dc + c * 8) * 2) ^ ((r & 7) << 4);
        *(bf16x8*)(Ks + off) = f;
      }
    }
    // ---- stage V block transposed: Vt[d][key] bf16, XOR-swizzled ----
    {
      #pragma unroll
      for (int it = 0; it < 4; ++it) {
        const int idx = tid + it * 256;
        const int d   = idx & 127;
        const int kgp = idx >> 7;  // 0..7, 8 keys each
        const float* vp = vg + ((size_t)(kb * 64 + kgp * 8) * HH + h) * DD + d;
        bf16x8 f;
        #pragma unroll
        for (int j = 0; j < 8; ++j) f[j] = (short)f2bf(vp[(size_t)j * HH * DD]);
        const int off = (d * 128 + kgp * 16) ^ ((d & 7) << 4);
        *(bf16x8*)(Vt + off) = f;
      }
    }
    __syncthreads();

    // ---- S = Q K^T : 16 q-rows x 64 keys per wave ----
    f32x4 s[4];
    #pragma unroll
    for (int n = 0; n < 4; ++n) {
      f32x4 acc = (f32x4){0.f, 0.f, 0.f, 0.f};
      const int key = n * 16 + l15;
      #pragma unroll
      for (int kc = 0; kc < 4; ++kc) {
        const int off = (key * 256 + (kc * 32 + lg * 8) * 2) ^ ((key & 7) << 4);
        bf16x8 kf = *(const bf16x8*)(Ks + off);
        acc = __builtin_amdgcn_mfma_f32_16x16x32_bf16(qa[kc], kf, acc, 0, 0, 0);
      }
      s[n] = acc;
    }

    // ---- diagonal block: element-level causal mask ----
    if (kb == qb) {
      #pragma unroll
      for (int n = 0; n < 4; ++n) {
        const int key = n * 16 + l15;
        #pragma unroll
        for (int r = 0; r < 4; ++r) {
          const int qr = wid * 16 + lg * 4 + r;
          if (qr < key) s[n][r] = -1e30f;
        }
      }
    }

    // ---- online softmax (row = lg*4+r, cols spread over 16 lanes x 4 tiles) ----
    float mnew[4], sc[4];
    #pragma unroll
    for (int r = 0; r < 4; ++r) {
      float mx = fmaxf(fmaxf(s[0][r], s[1][r]), fmaxf(s[2][r], s[3][r]));
      mx = fmaxf(mx, __shfl_xor(mx, 1));
      mx = fmaxf(mx, __shfl_xor(mx, 2));
      mx = fmaxf(mx, __shfl_xor(mx, 4));
      mx = fmaxf(mx, __shfl_xor(mx, 8));
      mnew[r] = fmaxf(mr[r], mx);
      sc[r] = __expf(mr[r] - mnew[r]);
      mr[r] = mnew[r];
    }
    #pragma unroll
    for (int r = 0; r < 4; ++r) {
      float acc = 0.f;
      #pragma unroll
      for (int n = 0; n < 4; ++n) {
        const float p = __expf(s[n][r] - mnew[r]);
        s[n][r] = p;
        acc += p;
      }
      acc += __shfl_xor(acc, 1);
      acc += __shfl_xor(acc, 2);
      acc += __shfl_xor(acc, 4);
      acc += __shfl_xor(acc, 8);
      lr[r] = lr[r] * sc[r] + acc;
    }
    #pragma unroll
    for (int nd = 0; nd < 8; ++nd) {
      #pragma unroll
      for (int r = 0; r < 4; ++r) oa[nd][r] *= sc[r];
    }

    // ---- P -> LDS (bf16, swizzled) to transpose into A-fragment layout ----
    #pragma unroll
    for (int n = 0; n < 4; ++n) {
      const int col = n * 16 + l15;
      #pragma unroll
      for (int r = 0; r < 4; ++r) {
        const int qr16 = lg * 4 + r;
        const int off = (qr16 * 128 + col * 2) ^ ((qr16 & 7) << 4);
        *(short*)(Pl + off) = (short)f2bf(s[n][r]);
      }
    }
    bf16x8 pa[2];
    #pragma unroll
    for (int kc = 0; kc < 2; ++kc) {
      const int off = (l15 * 128 + (kc * 32 + lg * 8) * 2) ^ ((l15 & 7) << 4);
      pa[kc] = *(const bf16x8*)(Pl + off);
    }

    // ---- O += P V ----
    #pragma unroll
    for (int nd = 0; nd < 8; ++nd) {
      const int d = nd * 16 + l15;
      #pragma unroll
      for (int kc = 0; kc < 2; ++kc) {
        const int off = (d * 128 + (kc * 32 + lg * 8) * 2) ^ ((d & 7) << 4);
        bf16x8 vf = *(const bf16x8*)(Vt + off);
        oa[nd] = __builtin_amdgcn_mfma_f32_16x16x32_bf16(pa[kc], vf, oa[nd], 0, 0, 0);
      }
    }
  }

  // ---- normalize and store fp32 ----
  float inv[4];
  #pragma unroll
  for (int r = 0; r < 4; ++r) inv[r] = 1.0f / lr[r];
  float* op = outg + ((size_t)(qb * 64) * HH + h) * DD;
  #pragma unroll
  for (int nd = 0; nd < 8; ++nd) {
    const int d = nd * 16 + l15;
    #pragma unroll
    for (int r = 0; r < 4; ++r) {
      const int qr = wid * 16 + lg * 4 + r;
      op[(size_t)qr * HH * DD + d] = oa[nd][r] * inv[r];
    }
  }
}

extern "C" void kernel_launch(void* const* d_in, const int* in_sizes, int n_in,
                              void* d_out, int out_size, void* d_ws, size_t ws_size,
                              hipStream_t stream) {
  const float* q    = (const float*)d_in[0];
  const float* k    = (const float*)d_in[1];
  const float* v    = (const float*)d_in[2];
  const int*   kidx = (const int*)d_in[3];
  float* out = (float*)d_out;
  const int kmax = in_sizes[3] / NBQ;   // = 8
  dim3 grid(NBQ, HH);
  sparse_attn_kernel<<<grid, 256, 0, stream>>>(q, k, v, kidx, out, kmax);
}